// Round 1
// baseline (206.029 us; speedup 1.0000x reference)
//
#include <hip/hip_runtime.h>

// SpatioConvLayer: B=16, C_IN=C_OUT=64, T=12, N=1024, KS=3
#define NB   16
#define NC   64
#define NT   12
#define NN   1024
#define NKS  3

typedef float  f32x4  __attribute__((ext_vector_type(4)));
typedef short  s16x8  __attribute__((ext_vector_type(8)));
typedef unsigned short u16x4 __attribute__((ext_vector_type(4)));
typedef unsigned short u16x8 __attribute__((ext_vector_type(8)));
typedef unsigned short ush;

__device__ __forceinline__ ush f2bf(float f) {
    union { float f; unsigned u; } v; v.f = f;
    unsigned r = v.u + 0x7FFFu + ((v.u >> 16) & 1u);   // RNE
    return (ush)(r >> 16);
}

// async 16-B global -> LDS (dest is wave-uniform base + lane*16)
__device__ __forceinline__ void cp16(const void* g, void* l) {
    __builtin_amdgcn_global_load_lds(
        (const __attribute__((address_space(1))) unsigned int*)g,
        (__attribute__((address_space(3))) unsigned int*)l, 16, 0, 0);
}

// Workspace layout (sizes unchanged):
//   apan @ 0        : bf16 A-panels [g4=48][kt=16][c=2048] x 16B   (25,165,824 B)
//                     c = row*8 + (d ^ (row&7)); row = bl*64 + ch (bl = bt-4*g4)
//                     d = K-subchunk (n = kt*64 + d*8 + i)
//   kb   @ 25165824 : bf16 B-panels [mt=16][kt=16][c=1536] x 16B   ( 6,291,456 B)
//                     c = j*8 + (d ^ (j&7)); j = k*64+mm
//   thbf @ 31457280 : bf16 theta^T [o=64][ck=192]                  (24,576 B)
#define APAN_OFF 0
#define KB_OFF   25165824
#define TH_OFF   31457280

// ---------------- prep: convert + transpose + swizzle once ----------------
// Block map: [0,1536) B-panels, [1536,1584) theta, [1584,7728) A-panels.
__global__ __launch_bounds__(256)
void spatio_prep(const float* __restrict__ x, const float* __restrict__ kern,
                 const float* __restrict__ theta,
                 ush* __restrict__ apan, ush* __restrict__ kb, ush* __restrict__ thbf)
{
    const int blk = blockIdx.x;
    const int tid = threadIdx.x;

    if (blk < 1536) {
        // ---- B panels: thread = one 16-B output chunk (linear writes) ----
        int ch   = blk * 256 + tid;            // (mt*16+kt)*1536 + c
        int rest = ch / 1536;
        int c    = ch - rest * 1536;
        int kt   = rest & 15, mtp = rest >> 4;
        int j    = c >> 3, pp = c & 7;
        int d    = pp ^ (j & 7);
        int k    = j >> 6, mm = j & 63;
        int col  = (k << 10) + (mtp << 6) + mm;
        int n0   = (kt << 6) + (d << 3);
        u16x8 w;
#pragma unroll
        for (int i = 0; i < 8; ++i)
            w[i] = f2bf(kern[(size_t)(n0 + i) * (NKS * NN) + col]);
        ((u16x8*)kb)[ch] = w;
    } else if (blk < 1584) {
        // ---- theta^T: thbf[o][k*64+c] ----
        int id = (blk - 1536) * 256 + tid;
        if (id < 12288) {
            int row = id >> 6, o = id & 63;   // row = c*3 + k
            int cc = row / 3, k = row - 3 * cc;
            thbf[o * 192 + k * 64 + cc] = f2bf(theta[id]);
        }
    } else {
        // ---- A panels: one 16-B chunk per thread (linear writes, coalesced reads) ----
        int id  = (blk - 1584) * 256 + tid;    // (g4*16+kt)*2048 + c
        int c   = id & 2047;
        int kt  = (id >> 11) & 15;
        int g4  = id >> 15;
        int row = c >> 3, pp = c & 7;
        int d   = pp ^ (row & 7);
        int bl  = row >> 6, cc = row & 63;
        int bt  = g4 * 4 + bl;
        int b   = bt / NT, t = bt - NT * b;
        const float* src = x + ((size_t)((b * NC + cc) * NT + t)) * NN + (kt << 6) + (d << 3);
        float4 a0 = ((const float4*)src)[0];
        float4 a1 = ((const float4*)src)[1];
        u16x8 w;
        w[0] = f2bf(a0.x); w[1] = f2bf(a0.y); w[2] = f2bf(a0.z); w[3] = f2bf(a0.w);
        w[4] = f2bf(a1.x); w[5] = f2bf(a1.y); w[6] = f2bf(a1.z); w[7] = f2bf(a1.w);
        ((u16x8*)apan)[id] = w;
    }
}

// ---------------- main: 256x192 tile, 4-phase K-steps, counted vmcnt ----------------
// 8 waves (4 bt-rows x 2 col-halves), per-wave 64x96 = 4x6 16x16 fragments.
// LDS: dbuf[p] @ p*57344 : As[256][64] (32 KB) + Bs[192][64] (24 KB); total 112 KB.
// Stage-2 overlay: xm[4][64][200] (100 KB) after the K-loop.
__global__ __launch_bounds__(512, 1)
void spatio_main(const ush* __restrict__ apan, const ush* __restrict__ kb,
                 const ush* __restrict__ thbf, const float* __restrict__ bias,
                 const float* __restrict__ x, float* __restrict__ out)
{
    __shared__ __attribute__((aligned(128))) char smem[114688];

    const int tid  = threadIdx.x;
    const int bid  = blockIdx.x;
    const int wg   = (bid & 7) * 96 + (bid >> 3);   // bijective XCD swizzle (768 = 8*96)
    const int g4   = wg >> 4;      // bt-quad 0..47
    const int mt   = wg & 15;      // m-tile 0..15
    const int lane = tid & 63;
    const int wid  = tid >> 6;     // 0..7
    const int wr   = wid >> 1;     // bt-row within block 0..3
    const int wn   = wid & 1;      // 96-col half 0..1
    const int quad = lane >> 4;
    const int l16  = lane & 15;
    const int swz  = l16 & 7;      // row&7 == l16&7 for all fragment rows

    const char* abase = (const char*)apan + ((size_t)g4 << 19);        // g4*16*2048*16
    const char* bbase = (const char*)kb   + ((size_t)mt * 393216);     // mt*16*1536*16

    f32x4 acc[4][6];
#pragma unroll
    for (int i = 0; i < 4; ++i)
#pragma unroll
        for (int j = 0; j < 6; ++j) acc[i][j] = (f32x4){0.f, 0.f, 0.f, 0.f};

    // stage K-tile tt (A 32 KB + B 24 KB = 7 cp16/thread) into dbuf[pp]
#define STAGE(tt, pp) do {                                                  \
        const char* as_ = abase + ((size_t)(tt) << 15);                     \
        const char* bs_ = bbase + (size_t)(tt) * 24576;                     \
        char* la_ = smem + (pp) * 57344;                                    \
        char* lb_ = la_ + 32768;                                            \
        _Pragma("unroll")                                                   \
        for (int i_ = 0; i_ < 4; ++i_)                                      \
            cp16(as_ + (i_ * 512 + tid) * 16, la_ + (i_ * 512 + tid) * 16); \
        _Pragma("unroll")                                                   \
        for (int i_ = 0; i_ < 3; ++i_)                                      \
            cp16(bs_ + (i_ * 512 + tid) * 16, lb_ + (i_ * 512 + tid) * 16); \
    } while (0)

    // prologue: tiles 0 and 1 in flight; wait only for tile 0 (vmcnt(7))
    STAGE(0, 0);
    STAGE(1, 1);
    asm volatile("s_waitcnt vmcnt(7)" ::: "memory");
    __builtin_amdgcn_s_barrier();
    asm volatile("" ::: "memory");

#pragma unroll 2
    for (int t = 0; t < 16; ++t) {
        const int p = t & 1;
        const ush (*As)[64] = (const ush (*)[64])(smem + p * 57344);
        const ush (*Bs)[64] = (const ush (*)[64])(smem + p * 57344 + 32768);
        s16x8 af[4];
#pragma unroll
        for (int kk = 0; kk < 2; ++kk)
#pragma unroll
            for (int g = 0; g < 2; ++g) {
                if (g == 0) {   // A-frags for this kk, reused across both jb-halves
#pragma unroll
                    for (int rb = 0; rb < 4; ++rb)
                        af[rb] = *(const s16x8*)&As[64 * wr + 16 * rb + l16]
                                                  [((kk * 4 + quad) ^ swz) << 3];
                }
                s16x8 bf[3];
#pragma unroll
                for (int jj = 0; jj < 3; ++jj)
                    bf[jj] = *(const s16x8*)&Bs[96 * wn + 48 * g + 16 * jj + l16]
                                               [((kk * 4 + quad) ^ swz) << 3];
                __builtin_amdgcn_s_setprio(1);
#pragma unroll
                for (int rb = 0; rb < 4; ++rb)
#pragma unroll
                    for (int jj = 0; jj < 3; ++jj)
                        acc[rb][3 * g + jj] = __builtin_amdgcn_mfma_f32_16x16x32_bf16(
                            af[rb], bf[jj], acc[rb][3 * g + jj], 0, 0, 0);
                __builtin_amdgcn_s_setprio(0);
                if (!(kk == 1 && g == 1)) {   // phase barrier (3 per tile)
                    asm volatile("" ::: "memory");
                    __builtin_amdgcn_s_barrier();
                    asm volatile("" ::: "memory");
                }
            }
        // tile end: my LDS reads fully serviced, then block-wide fence -> dbuf[p] free
        asm volatile("s_waitcnt lgkmcnt(0)" ::: "memory");
        __builtin_amdgcn_s_barrier();
        asm volatile("" ::: "memory");
        if (t < 14) {
            STAGE(t + 2, p);                               // earliest legal issue
            asm volatile("s_waitcnt vmcnt(7)" ::: "memory"); // retire tile t+1's loads only
            __builtin_amdgcn_s_barrier();
            asm volatile("" ::: "memory");
        } else if (t == 14) {
            asm volatile("s_waitcnt vmcnt(0)" ::: "memory"); // drain tile 15 (last)
            __builtin_amdgcn_s_barrier();
            asm volatile("" ::: "memory");
        }
    }
#undef STAGE

    // ===== stage 2: xm for all 4 bt at once, overlaying the K-loop buffers =====
    ush (*xm)[64][200] = (ush (*)[64][200])smem;   // [bt][mm][ck], 102,400 B
#pragma unroll
    for (int rb = 0; rb < 4; ++rb)
#pragma unroll
        for (int jb = 0; jb < 6; ++jb) {
            int J   = 96 * wn + 16 * jb + l16;
            int kk2 = J >> 6, mm = J & 63;
            int ck0 = (kk2 << 6) + 16 * rb + (quad << 2);
            u16x4 w;
            w.x = f2bf(acc[rb][jb].x); w.y = f2bf(acc[rb][jb].y);
            w.z = f2bf(acc[rb][jb].z); w.w = f2bf(acc[rb][jb].w);
            *(u16x4*)&xm[wr][mm][ck0] = w;
        }
    __syncthreads();

    // gc = th^T @ xm : wave wid -> bt = wid&3, mm-half = wid>>2; o = 0..63
    const int bt2 = wid & 3, hh = wid >> 2;
    f32x4 acc2[4][2];
#pragma unroll
    for (int i = 0; i < 4; ++i) {
        acc2[i][0] = (f32x4){0.f, 0.f, 0.f, 0.f};
        acc2[i][1] = (f32x4){0.f, 0.f, 0.f, 0.f};
    }
#pragma unroll
    for (int ks = 0; ks < 6; ++ks) {       // K = 192
        s16x8 b2[2];
#pragma unroll
        for (int jm = 0; jm < 2; ++jm)
            b2[jm] = *(const s16x8*)&xm[bt2][(hh << 5) + (jm << 4) + l16]
                                            [(ks << 5) + (quad << 3)];
#pragma unroll
        for (int of = 0; of < 4; ++of) {
            s16x8 a2 = *(const s16x8*)(thbf + (size_t)((of << 4) + l16) * 192
                                            + (ks << 5) + (quad << 3));
#pragma unroll
            for (int jm = 0; jm < 2; ++jm)
                acc2[of][jm] = __builtin_amdgcn_mfma_f32_16x16x32_bf16(
                    a2, b2[jm], acc2[of][jm], 0, 0, 0);
        }
    }

    // epilogue: out = relu(gc + bias + x), residual read as f32 from x directly
    const int bt = (g4 << 2) + bt2;
    const int b  = bt / NT, tt = bt - NT * b;
#pragma unroll
    for (int of = 0; of < 4; ++of)
#pragma unroll
        for (int jm = 0; jm < 2; ++jm) {
            int mm = (hh << 5) + (jm << 4) + l16;
#pragma unroll
            for (int r = 0; r < 4; ++r) {
                int o = (of << 4) + (quad << 2) + r;
                size_t idx = ((size_t)((b * NC + o) * NT + tt)) * NN + (mt << 6) + mm;
                float v = acc2[of][jm][r] + bias[o] + x[idx];
                out[idx] = fmaxf(v, 0.f);
            }
        }
}

extern "C" void kernel_launch(void* const* d_in, const int* in_sizes, int n_in,
                              void* d_out, int out_size, void* d_ws, size_t ws_size,
                              hipStream_t stream) {
    const float* x     = (const float*)d_in[0];
    const float* kern  = (const float*)d_in[1];
    const float* theta = (const float*)d_in[2];
    const float* bias  = (const float*)d_in[3];
    float* out = (float*)d_out;
    (void)in_sizes; (void)n_in; (void)out_size; (void)ws_size;

    ush* apan = (ush*)((char*)d_ws + APAN_OFF);
    ush* kbp  = (ush*)((char*)d_ws + KB_OFF);
    ush* thbf = (ush*)((char*)d_ws + TH_OFF);

    hipLaunchKernelGGL(spatio_prep, dim3(7728), dim3(256), 0, stream,
                       x, kern, theta, apan, kbp, thbf);
    hipLaunchKernelGGL(spatio_main, dim3(768), dim3(512), 0, stream,
                       apan, kbp, thbf, bias, x, out);
}

// Round 2
// 189.458 us; speedup vs baseline: 1.0875x; 1.0875x over previous
//
#include <hip/hip_runtime.h>

// SpatioConvLayer: B=16, C_IN=C_OUT=64, T=12, N=1024, KS=3
#define NB   16
#define NC   64
#define NT   12
#define NN   1024
#define NKS  3

typedef float  f32x4  __attribute__((ext_vector_type(4)));
typedef short  s16x8  __attribute__((ext_vector_type(8)));
typedef unsigned short u16x4 __attribute__((ext_vector_type(4)));
typedef unsigned short u16x8 __attribute__((ext_vector_type(8)));
typedef unsigned short ush;

__device__ __forceinline__ ush f2bf(float f) {
    union { float f; unsigned u; } v; v.f = f;
    unsigned r = v.u + 0x7FFFu + ((v.u >> 16) & 1u);   // RNE
    return (ush)(r >> 16);
}
__device__ __forceinline__ float bf2f(ush h) {
    union { unsigned u; float f; } v; v.u = ((unsigned)h) << 16;
    return v.f;
}

// async 16-B global -> LDS (dest must be wave-uniform base + lane*16)
__device__ __forceinline__ void cp16(const void* g, void* l) {
    __builtin_amdgcn_global_load_lds(
        (const __attribute__((address_space(1))) unsigned int*)g,
        (__attribute__((address_space(3))) unsigned int*)l, 16, 0, 0);
}

// Workspace layout:
//   apan @ 0        : bf16 A-panels [g2=96][nb=32][slot=512] x 16B  (25,165,824 B)
//                     slot = row*4 + p ; row = bl*64+c (bl = bt-2*g2) ; p = d ^ (row&3)
//   kb   @ 25165824 : bf16 B-panels [mt=16][nb=32][slot=768] x 16B  (6,291,456 B)
//                     slot = j*4 + p ; j = k*64+mm ; p = d ^ (j&3)
//   thbf @ 31457280 : bf16 theta^T [o=64][ck=192]                   (24,576 B)
#define APAN_OFF 0
#define KB_OFF   25165824
#define TH_OFF   31457280

// ---------------- prep: convert + transpose + swizzle once ----------------
// Block map: [0,6144) A-panels, [6144,6528) B-panels (coalesced transpose),
//            [6528,6576) theta.
__global__ __launch_bounds__(256)
void spatio_prep(const float* __restrict__ x, const float* __restrict__ kern,
                 const float* __restrict__ theta,
                 ush* __restrict__ apan, ush* __restrict__ kb, ush* __restrict__ thbf)
{
    const int blk = blockIdx.x;
    const int tid = threadIdx.x;

    if (blk < 6144) {
        // ---- A panels: one 16-B slot per thread (linear writes, coalesced reads) ----
        int id   = blk * 256 + tid;
        int slot = id & 511;
        int g2nb = id >> 9;
        int nb   = g2nb & 31, g2 = g2nb >> 5;
        int row  = slot >> 2, p = slot & 3;
        int d    = p ^ (row & 3);
        int bl   = row >> 6, c = row & 63;
        int bt   = 2 * g2 + bl;
        int b    = bt / NT, t = bt - NT * b;
        const float* src = x + ((size_t)((b * NC + c) * NT + t)) * NN + nb * 32 + d * 8;
        float4 a0 = ((const float4*)src)[0];
        float4 a1 = ((const float4*)src)[1];
        u16x8 w;
        w[0] = f2bf(a0.x); w[1] = f2bf(a0.y); w[2] = f2bf(a0.z); w[3] = f2bf(a0.w);
        w[4] = f2bf(a1.x); w[5] = f2bf(a1.y); w[6] = f2bf(a1.z); w[7] = f2bf(a1.w);
        ((u16x8*)apan)[id] = w;
    } else if (blk < 6528) {
        // ---- B panels: coalesced both ways ----
        // unit = (mt,nb); 192 threads/unit (exactly 3 waves, wave-uniform k).
        // thread = (k, jqm, d): reads 8 float4s (4 consecutive cols x 8 rows;
        // per wave-step 4 fully-consumed 256-B segments -> zero overfetch),
        // writes 4 x 16-B chunks inside one 64-B line.
        unsigned id2 = (unsigned)(blk - 6144) * 256u + (unsigned)tid;  // 0..98303
        unsigned unit = id2 / 192u;
        int t    = (int)(id2 - unit * 192u);
        int mt   = (int)(unit >> 5), nb = (int)(unit & 31u);
        int k    = t >> 6, r = t & 63;
        int jqm  = r >> 2, d = r & 3;
        int colbase = (k << 10) + (mt << 6) + (jqm << 2);
        float4 v[8];
#pragma unroll
        for (int i = 0; i < 8; ++i)
            v[i] = *(const float4*)&kern[(size_t)(nb * 32 + d * 8 + i) * (NKS * NN) + colbase];
        int cbase = (mt * 32 + nb) * 768 + (k * 64 + jqm * 4) * 4;
#pragma unroll
        for (int jj = 0; jj < 4; ++jj) {
            u16x8 w;
            w[0] = f2bf(v[0][jj]); w[1] = f2bf(v[1][jj]);
            w[2] = f2bf(v[2][jj]); w[3] = f2bf(v[3][jj]);
            w[4] = f2bf(v[4][jj]); w[5] = f2bf(v[5][jj]);
            w[6] = f2bf(v[6][jj]); w[7] = f2bf(v[7][jj]);
            ((u16x8*)kb)[cbase + jj * 4 + (d ^ jj)] = w;
        }
    } else {
        // ---- theta^T: thbf[o][k*64+c] ----
        int id = (blk - 6528) * 256 + tid;
        if (id < 12288) {
            int row = id >> 6, o = id & 63;   // row = c*3 + k
            int c = row / 3, k = row - 3 * c;
            thbf[o * 192 + k * 64 + c] = f2bf(theta[id]);
        }
    }
}

// ---------------- main: 128x192 tile, double-buffered 1-barrier K-loop ----------------
__global__ __launch_bounds__(256, 2)
void spatio_main(const ush* __restrict__ apan, const ush* __restrict__ kb,
                 const ush* __restrict__ thbf, const float* __restrict__ bias,
                 float* __restrict__ out)
{
    // LDS: buf[p] @ p*20480 : As[128][32] (8 KB) + Bs[192][32] (12 KB)
    //      stash @40960: stL[128][32] + stH[128][32] (16 KB, persists)
    //      stage2 xm[64][200] overlays @0 (25.6 KB) after stage 1
    __shared__ __attribute__((aligned(128))) char smem[57344];
    ush (*xm)[200] = (ush (*)[200])smem;
    ush (*stL)[32] = (ush (*)[32])(smem + 40960);
    ush (*stH)[32] = (ush (*)[32])(smem + 49152);

    const int tid  = threadIdx.x;
    const int g2   = blockIdx.x;          // bt-pair 0..95
    const int mt   = blockIdx.y;          // m-tile 0..15
    const int m_base = mt * 64;
    const int lane = tid & 63;
    const int wid  = tid >> 6;            // 0..3
    const int wr   = wid & 1;             // bt half (64 rows)
    const int wn   = wid >> 1;            // col half (96 j)
    const int quad = lane >> 4;
    const int l16  = lane & 15;
    const int pofs = (quad ^ (l16 & 3)) * 8;   // swizzled 16-B chunk (u16 units)

    const char* apan_c = (const char*)apan + ((size_t)g2 << 18);        // g2*32*512*16
    const char* kb_c   = (const char*)kb + ((size_t)mt * 32 * 768 * 16);

    f32x4 acc[4][6];
#pragma unroll
    for (int i = 0; i < 4; ++i)
#pragma unroll
        for (int j = 0; j < 6; ++j) acc[i][j] = (f32x4){0.f, 0.f, 0.f, 0.f};

    // prologue: preload iter 0 into buf0
#pragma unroll
    for (int i = 0; i < 2; ++i)
        cp16(apan_c + (i * 256 + tid) * 16, smem + (i * 256 + tid) * 16);
#pragma unroll
    for (int i = 0; i < 3; ++i)
        cp16(kb_c + (i * 256 + tid) * 16, smem + 8192 + (i * 256 + tid) * 16);

    // ===== stage 1: xm = x @ K ; 32 iters, 1 barrier/iter, dbuf =====
    for (int it = 0; it < 32; ++it) {
        const int p = it & 1;
        char* buf = smem + p * 20480;
        __syncthreads();                   // buf[p] loads complete; buf[p^1] readers (it-1) done
        if (it < 31) {                     // prefetch it+1 into buf[p^1]
            const char* asrc = apan_c + ((size_t)(it + 1) << 13);
            const char* bsrc = kb_c + (size_t)(it + 1) * 12288;
            char* nbuf = smem + (p ^ 1) * 20480;
#pragma unroll
            for (int i = 0; i < 2; ++i)
                cp16(asrc + (i * 256 + tid) * 16, nbuf + (i * 256 + tid) * 16);
#pragma unroll
            for (int i = 0; i < 3; ++i)
                cp16(bsrc + (i * 256 + tid) * 16, nbuf + 8192 + (i * 256 + tid) * 16);
        }
        if ((it >> 1) == mt) {
            // stash de-swizzled residual tile (bf16 x rows for this m-tile)
            const char* asrc = apan_c + ((size_t)it << 13);
            char* sb = smem + 40960 + (it & 1) * 8192;
#pragma unroll
            for (int i = 0; i < 2; ++i) {
                int m = i * 256 + tid;
                int slot = (m & ~3) + ((m & 3) ^ ((m >> 2) & 3));
                cp16(asrc + slot * 16, sb + m * 16);
            }
        }

        ush (*As)[32] = (ush (*)[32])buf;
        ush (*Bs)[32] = (ush (*)[32])(buf + 8192);
        s16x8 af[4], bf[6];
#pragma unroll
        for (int rb = 0; rb < 4; ++rb)
            af[rb] = *(const s16x8*)&As[64 * wr + 16 * rb + l16][pofs];
#pragma unroll
        for (int jb = 0; jb < 6; ++jb)
            bf[jb] = *(const s16x8*)&Bs[96 * wn + 16 * jb + l16][pofs];
#pragma unroll
        for (int rb = 0; rb < 4; ++rb)
#pragma unroll
            for (int jb = 0; jb < 6; ++jb)
                acc[rb][jb] = __builtin_amdgcn_mfma_f32_16x16x32_bf16(af[rb], bf[jb], acc[rb][jb], 0, 0, 0);
    }

    // ===== stage 2: gc = th^T @ xm ; one bt per pass =====
    float bo[4];
#pragma unroll
    for (int r = 0; r < 4; ++r) bo[r] = bias[16 * wid + 4 * quad + r];

    for (int pass = 0; pass < 2; ++pass) {
        __syncthreads();               // stage-1/previous-pass LDS reads done
        if (wr == pass) {
            // write acc -> xm[mm][k*64+c] (B-operand layout)
#pragma unroll
            for (int rb = 0; rb < 4; ++rb)
#pragma unroll
                for (int jb = 0; jb < 6; ++jb) {
                    int J  = 96 * wn + 16 * jb + l16;
                    int kk = J >> 6, mm = J & 63;
                    int ck0 = kk * 64 + 16 * rb + 4 * quad;
                    u16x4 w;
                    w.x = f2bf(acc[rb][jb].x); w.y = f2bf(acc[rb][jb].y);
                    w.z = f2bf(acc[rb][jb].z); w.w = f2bf(acc[rb][jb].w);
                    *(u16x4*)&xm[mm][ck0] = w;
                }
        }
        __syncthreads();

        f32x4 acc2[4];
#pragma unroll
        for (int jb = 0; jb < 4; ++jb) acc2[jb] = (f32x4){0.f, 0.f, 0.f, 0.f};
#pragma unroll
        for (int ks = 0; ks < 6; ++ks) {       // K = 192
            s16x8 a2 = *(const s16x8*)(thbf + (size_t)(16 * wid + l16) * 192 + ks * 32 + quad * 8);
#pragma unroll
            for (int jb = 0; jb < 4; ++jb) {
                s16x8 b2 = *(const s16x8*)&xm[16 * jb + l16][ks * 32 + quad * 8];
                acc2[jb] = __builtin_amdgcn_mfma_f32_16x16x32_bf16(a2, b2, acc2[jb], 0, 0, 0);
            }
        }

        // epilogue: out = relu(gc + bias + x_bf16) ; residual from LDS stash
        const int bt = 2 * g2 + pass;
        const int b2i = bt / NT, t2 = bt - NT * b2i;
#pragma unroll
        for (int jb = 0; jb < 4; ++jb) {
            int mm = 16 * jb + l16;
#pragma unroll
            for (int r = 0; r < 4; ++r) {
                int o = 16 * wid + 4 * quad + r;
                int row = pass * 64 + o;
                ush rv = (jb < 2) ? stL[row][mm] : stH[row][mm - 32];
                size_t idx = (((size_t)(b2i * NC + o) * NT + t2) * NN) + m_base + mm;
                float v = acc2[jb][r] + bo[r] + bf2f(rv);
                out[idx] = fmaxf(v, 0.f);
            }
        }
    }
}

extern "C" void kernel_launch(void* const* d_in, const int* in_sizes, int n_in,
                              void* d_out, int out_size, void* d_ws, size_t ws_size,
                              hipStream_t stream) {
    const float* x     = (const float*)d_in[0];
    const float* kern  = (const float*)d_in[1];
    const float* theta = (const float*)d_in[2];
    const float* bias  = (const float*)d_in[3];
    float* out = (float*)d_out;
    (void)in_sizes; (void)n_in; (void)out_size; (void)ws_size;

    ush* apan = (ush*)((char*)d_ws + APAN_OFF);
    ush* kbp  = (ush*)((char*)d_ws + KB_OFF);
    ush* thbf = (ush*)((char*)d_ws + TH_OFF);

    hipLaunchKernelGGL(spatio_prep, dim3(6576), dim3(256), 0, stream,
                       x, kern, theta, apan, kbp, thbf);
    hipLaunchKernelGGL(spatio_main, dim3(96, 16), dim3(256), 0, stream,
                       apan, kbp, thbf, bias, out);
}